// Round 2
// baseline (256.988 us; speedup 1.0000x reference)
//
#include <hip/hip_runtime.h>
#include <math.h>

#define BLOCK 256
#define XW 13
#define PW 30
#define NX4 (BLOCK * XW / 4)   // 832 float4 per x-tile
#define NP4 (BLOCK * PW / 4)   // 1920 float4 per params-tile

// Per-patient derivative. X[13] states, P[30] params (column order per reference).
__device__ __forceinline__ void dxdt(const float* X, const float* P,
                                     float ai, float cho, float lq, float lf,
                                     float* dx)
{
    const float BW = P[0],  KMAX = P[1],  B   = P[2],  D   = P[3],  KMIN = P[4];
    const float KABS = P[5], F   = P[6],  KP1 = P[7],  KP2 = P[8],  KP3  = P[9];
    const float FSNC = P[10], KE1 = P[11], KE2 = P[12], K1 = P[13], K2   = P[14];
    const float VM0 = P[15], VMX = P[16], KM0 = P[17], M1 = P[18], M2   = P[19];
    const float M4  = P[20], KA1 = P[21], KA2 = P[22], VI = P[23], P2U  = P[24];
    const float IB  = P[25], KI  = P[26], M30 = P[27], KD = P[28], KSC  = P[29];

    const float f_insulin = ai * 6000.0f / BW;
    const float qsto = X[0] + X[1];
    const float Dbar = lq + lf;

    dx[0] = -KMAX * X[0] + cho * 1000.0f;

    const float inv_dbar = 1.0f / (Dbar + 1e-7f);
    const float aa = 2.5f / (1.0f - B) * inv_dbar;
    const float cc = 2.5f / D * inv_dbar;
    const float kgut_true = KMIN + (KMAX - KMIN) * 0.5f *
        (tanhf(aa * (qsto - B * Dbar)) - tanhf(cc * (qsto - D * Dbar)) + 2.0f);
    const float kgut = (Dbar > 0.0f) ? kgut_true : KMAX;

    dx[1] = KMAX * X[0] - X[1] * kgut;
    dx[2] = kgut * X[1] - KABS * X[2];

    const float Rat  = F * KABS * X[2] / BW;
    const float EGPt = KP1 - KP2 * X[3] - KP3 * X[8];
    const float Et   = (X[3] > KE2) ? KE1 * (X[3] - KE2) : 0.0f;
    const float d3 = fmaxf(EGPt, 0.0f) + Rat - FSNC - Et - K1 * X[3] + K2 * X[4];
    dx[3] = (X[3] >= 0.0f) ? d3 : 0.0f;

    const float Vmt  = VM0 + VMX * X[6];
    const float Uidt = Vmt * X[4] / (KM0 + X[4]);
    const float d4 = -Uidt + K1 * X[3] - K2 * X[4];
    dx[4] = (X[4] >= 0.0f) ? d4 : 0.0f;

    const float d5 = -(M2 + M4) * X[5] + M1 * X[9] + KA1 * X[10] + KA2 * X[11];
    const float It = X[5] / VI;
    dx[5] = (X[5] >= 0.0f) ? d5 : 0.0f;

    dx[6] = -P2U * X[6] + P2U * (It - IB);
    dx[7] = -KI * (X[7] - It);
    dx[8] = -KI * (X[8] - X[7]);

    const float d9 = -(M1 + M30) * X[9] + M2 * X[5];
    dx[9] = (X[9] >= 0.0f) ? d9 : 0.0f;

    const float d10 = f_insulin - (KA1 + KD) * X[10];
    dx[10] = (X[10] >= 0.0f) ? d10 : 0.0f;

    const float d11 = KD * X[10] - KA2 * X[11];
    dx[11] = (X[11] >= 0.0f) ? d11 : 0.0f;

    const float d12 = -KSC * X[12] + KSC * X[3];
    dx[12] = (X[12] >= 0.0f) ? d12 : 0.0f;
}

__global__ __launch_bounds__(BLOCK) void t1d_kernel(
    const float* __restrict__ x,
    const float* __restrict__ params,
    const float* __restrict__ action_ins,
    const float* __restrict__ action_CHO,
    const float* __restrict__ last_Qsto,
    const float* __restrict__ last_foodtaken,
    float* __restrict__ out, int n)
{
    // 44 KB LDS -> 3 blocks/CU (12 waves). x tile doubles as output staging.
    __shared__ float xbuf[BLOCK * XW];   // 13312 B
    __shared__ float pbuf[BLOCK * PW];   // 30720 B

    const int tid = threadIdx.x;
    const size_t base = (size_t)blockIdx.x * BLOCK;

    if (base + BLOCK <= (size_t)n) {
        const float4* xg = (const float4*)(x + base * XW);       // 16B-aligned
        const float4* pg = (const float4*)(params + base * PW);  // 16B-aligned
        float4* xl = (float4*)xbuf;
        float4* pl = (float4*)pbuf;

        // ---- BATCHED staging: issue ALL global loads before any ds_write ----
        // (R1 lesson: rolled load->ds_write loop serialized ~11 HBM round
        //  trips per block; batching keeps ~12 loads in flight per thread.)
        float4 xr0 = xg[tid];
        float4 xr1 = xg[tid + 256];
        float4 xr2 = xg[tid + 512];
        float4 xr3;                       // 832 = 3*256 + 64
        if (tid < 64) xr3 = xg[tid + 768];

        float4 pr[8];                     // 1920 = 7*256 + 128
        #pragma unroll
        for (int i = 0; i < 7; ++i) pr[i] = pg[tid + i * 256];
        if (tid < 128) pr[7] = pg[tid + 7 * 256];

        const float ai  = action_ins[base + tid];
        const float cho = action_CHO[base + tid];
        const float lq  = last_Qsto[base + tid];
        const float lf  = last_foodtaken[base + tid];

        // ---- now spill to LDS (compiler uses fine-grained vmcnt waits) ----
        xl[tid]       = xr0;
        xl[tid + 256] = xr1;
        xl[tid + 512] = xr2;
        if (tid < 64) xl[tid + 768] = xr3;
        #pragma unroll
        for (int i = 0; i < 7; ++i) pl[tid + i * 256] = pr[i];
        if (tid < 128) pl[tid + 7 * 256] = pr[7];

        __syncthreads();

        // ---- per-row LDS reads (stride 13 odd: <=2-way, free; stride 30: 4-way, cheap) ----
        float X[XW], P[PW], dx[XW];
        #pragma unroll
        for (int j = 0; j < XW; ++j) X[j] = xbuf[tid * XW + j];
        #pragma unroll
        for (int j = 0; j < PW; ++j) P[j] = pbuf[tid * PW + j];

        dxdt(X, P, ai, cho, lq, lf, dx);

        // own-row overwrite; cross-thread reads only after the barrier
        #pragma unroll
        for (int j = 0; j < XW; ++j) xbuf[tid * XW + j] = dx[j];

        __syncthreads();

        // ---- batched store: LDS -> registers -> coalesced float4 global ----
        float4 o0 = xl[tid];
        float4 o1 = xl[tid + 256];
        float4 o2 = xl[tid + 512];
        float4 o3;
        if (tid < 64) o3 = xl[tid + 768];
        float4* og = (float4*)(out + base * XW);
        og[tid]       = o0;
        og[tid + 256] = o1;
        og[tid + 512] = o2;
        if (tid < 64) og[tid + 768] = o3;
    } else {
        // tail block (not hit for N=2^20): scalar path
        const size_t i = base + tid;
        if (i < (size_t)n) {
            float X[XW], P[PW], dx[XW];
            #pragma unroll
            for (int j = 0; j < XW; ++j) X[j] = x[i * XW + j];
            #pragma unroll
            for (int j = 0; j < PW; ++j) P[j] = params[i * PW + j];
            dxdt(X, P, action_ins[i], action_CHO[i], last_Qsto[i],
                 last_foodtaken[i], dx);
            #pragma unroll
            for (int j = 0; j < XW; ++j) out[i * XW + j] = dx[j];
        }
    }
}

extern "C" void kernel_launch(void* const* d_in, const int* in_sizes, int n_in,
                              void* d_out, int out_size, void* d_ws, size_t ws_size,
                              hipStream_t stream) {
    const float* x      = (const float*)d_in[0];
    const float* params = (const float*)d_in[1];
    const float* ai     = (const float*)d_in[2];
    const float* cho    = (const float*)d_in[3];
    const float* lq     = (const float*)d_in[4];
    const float* lf     = (const float*)d_in[5];
    float* out = (float*)d_out;

    const int n = in_sizes[0] / XW;          // number of patients
    const int grid = (n + BLOCK - 1) / BLOCK;
    t1d_kernel<<<grid, BLOCK, 0, stream>>>(x, params, ai, cho, lq, lf, out, n);
}

// Round 3
// 247.651 us; speedup vs baseline: 1.0377x; 1.0377x over previous
//
#include <hip/hip_runtime.h>
#include <math.h>

#define BLOCK 256
#define XW 13
#define PW 30
#define XCHUNKS (BLOCK * XW / 4 / 64)   // 13 chunks of 64 float4 per x-tile
#define PCHUNKS (BLOCK * PW / 4 / 64)   // 30 chunks of 64 float4 per params-tile

#define AS1(p) ((__attribute__((address_space(1))) void*)(p))
#define AS3(p) ((__attribute__((address_space(3))) void*)(p))

// Per-patient derivative. X[13] states, P[30] params (column order per reference).
__device__ __forceinline__ void dxdt(const float* X, const float* P,
                                     float ai, float cho, float lq, float lf,
                                     float* dx)
{
    const float BW = P[0],  KMAX = P[1],  B   = P[2],  D   = P[3],  KMIN = P[4];
    const float KABS = P[5], F   = P[6],  KP1 = P[7],  KP2 = P[8],  KP3  = P[9];
    const float FSNC = P[10], KE1 = P[11], KE2 = P[12], K1 = P[13], K2   = P[14];
    const float VM0 = P[15], VMX = P[16], KM0 = P[17], M1 = P[18], M2   = P[19];
    const float M4  = P[20], KA1 = P[21], KA2 = P[22], VI = P[23], P2U  = P[24];
    const float IB  = P[25], KI  = P[26], M30 = P[27], KD = P[28], KSC  = P[29];

    const float f_insulin = ai * 6000.0f / BW;
    const float qsto = X[0] + X[1];
    const float Dbar = lq + lf;

    dx[0] = -KMAX * X[0] + cho * 1000.0f;

    const float inv_dbar = 1.0f / (Dbar + 1e-7f);
    const float aa = 2.5f / (1.0f - B) * inv_dbar;
    const float cc = 2.5f / D * inv_dbar;
    const float kgut_true = KMIN + (KMAX - KMIN) * 0.5f *
        (tanhf(aa * (qsto - B * Dbar)) - tanhf(cc * (qsto - D * Dbar)) + 2.0f);
    const float kgut = (Dbar > 0.0f) ? kgut_true : KMAX;

    dx[1] = KMAX * X[0] - X[1] * kgut;
    dx[2] = kgut * X[1] - KABS * X[2];

    const float Rat  = F * KABS * X[2] / BW;
    const float EGPt = KP1 - KP2 * X[3] - KP3 * X[8];
    const float Et   = (X[3] > KE2) ? KE1 * (X[3] - KE2) : 0.0f;
    const float d3 = fmaxf(EGPt, 0.0f) + Rat - FSNC - Et - K1 * X[3] + K2 * X[4];
    dx[3] = (X[3] >= 0.0f) ? d3 : 0.0f;

    const float Vmt  = VM0 + VMX * X[6];
    const float Uidt = Vmt * X[4] / (KM0 + X[4]);
    const float d4 = -Uidt + K1 * X[3] - K2 * X[4];
    dx[4] = (X[4] >= 0.0f) ? d4 : 0.0f;

    const float d5 = -(M2 + M4) * X[5] + M1 * X[9] + KA1 * X[10] + KA2 * X[11];
    const float It = X[5] / VI;
    dx[5] = (X[5] >= 0.0f) ? d5 : 0.0f;

    dx[6] = -P2U * X[6] + P2U * (It - IB);
    dx[7] = -KI * (X[7] - It);
    dx[8] = -KI * (X[8] - X[7]);

    const float d9 = -(M1 + M30) * X[9] + M2 * X[5];
    dx[9] = (X[9] >= 0.0f) ? d9 : 0.0f;

    const float d10 = f_insulin - (KA1 + KD) * X[10];
    dx[10] = (X[10] >= 0.0f) ? d10 : 0.0f;

    const float d11 = KD * X[10] - KA2 * X[11];
    dx[11] = (X[11] >= 0.0f) ? d11 : 0.0f;

    const float d12 = -KSC * X[12] + KSC * X[3];
    dx[12] = (X[12] >= 0.0f) ? d12 : 0.0f;
}

__global__ __launch_bounds__(BLOCK) void t1d_kernel(
    const float* __restrict__ x,
    const float* __restrict__ params,
    const float* __restrict__ action_ins,
    const float* __restrict__ action_CHO,
    const float* __restrict__ last_Qsto,
    const float* __restrict__ last_foodtaken,
    float* __restrict__ out, int n)
{
    // 44 KB LDS -> 3 blocks/CU (12 waves). x tile doubles as output staging.
    __shared__ float xbuf[BLOCK * XW];   // 13312 B
    __shared__ float pbuf[BLOCK * PW];   // 30720 B

    const int tid  = threadIdx.x;
    const int lane = tid & 63;
    const int wave = tid >> 6;           // 0..3
    const size_t base = (size_t)blockIdx.x * BLOCK;

    if (base + BLOCK <= (size_t)n) {
        // ---- async DMA staging: global -> LDS, zero VGPR round-trip ----
        // (R2 lesson: register batching spilled to scratch — +120 MiB HBM
        //  writes. global_load_lds is fire-and-forget; each wave keeps ~11
        //  1-KiB loads in flight with no intermediate waits.)
        // Layout matches the HW constraint exactly: LDS dest = uniform base
        // + lane*16, global src = lane-contiguous float4.
        const float4* xg = (const float4*)(x + base * XW);       // 16B-aligned
        const float4* pg = (const float4*)(params + base * PW);  // 16B-aligned
        float4* xl = (float4*)xbuf;
        float4* pl = (float4*)pbuf;

        for (int c = wave; c < XCHUNKS; c += 4)                  // 13 chunks
            __builtin_amdgcn_global_load_lds(AS1(xg + c * 64 + lane),
                                             AS3(xl + c * 64), 16, 0, 0);
        for (int c = wave; c < PCHUNKS; c += 4)                  // 30 chunks
            __builtin_amdgcn_global_load_lds(AS1(pg + c * 64 + lane),
                                             AS3(pl + c * 64), 16, 0, 0);

        // per-patient scalars: coalesced dword loads into registers
        const float ai  = action_ins[base + tid];
        const float cho = action_CHO[base + tid];
        const float lq  = last_Qsto[base + tid];
        const float lf  = last_foodtaken[base + tid];

        __syncthreads();   // single vmcnt(0) drain for all DMA loads

        // ---- per-row LDS reads (stride 13 odd: <=2-way, free; stride 30: 4-way, cheap) ----
        float X[XW], P[PW], dx[XW];
        #pragma unroll
        for (int j = 0; j < XW; ++j) X[j] = xbuf[tid * XW + j];
        #pragma unroll
        for (int j = 0; j < PW; ++j) P[j] = pbuf[tid * PW + j];

        dxdt(X, P, ai, cho, lq, lf, dx);

        // own-row overwrite; cross-thread reads only after the barrier
        #pragma unroll
        for (int j = 0; j < XW; ++j) xbuf[tid * XW + j] = dx[j];

        __syncthreads();

        // ---- coalesced float4 store: LDS -> global (stores are fire-and-forget) ----
        float4* og = (float4*)(out + base * XW);
        og[tid]       = xl[tid];
        og[tid + 256] = xl[tid + 256];
        og[tid + 512] = xl[tid + 512];
        if (tid < 64) og[tid + 768] = xl[tid + 768];
    } else {
        // tail block (not hit for N=2^20): scalar path
        const size_t i = base + tid;
        if (i < (size_t)n) {
            float X[XW], P[PW], dx[XW];
            #pragma unroll
            for (int j = 0; j < XW; ++j) X[j] = x[i * XW + j];
            #pragma unroll
            for (int j = 0; j < PW; ++j) P[j] = params[i * PW + j];
            dxdt(X, P, action_ins[i], action_CHO[i], last_Qsto[i],
                 last_foodtaken[i], dx);
            #pragma unroll
            for (int j = 0; j < XW; ++j) out[i * XW + j] = dx[j];
        }
    }
}

extern "C" void kernel_launch(void* const* d_in, const int* in_sizes, int n_in,
                              void* d_out, int out_size, void* d_ws, size_t ws_size,
                              hipStream_t stream) {
    const float* x      = (const float*)d_in[0];
    const float* params = (const float*)d_in[1];
    const float* ai     = (const float*)d_in[2];
    const float* cho    = (const float*)d_in[3];
    const float* lq     = (const float*)d_in[4];
    const float* lf     = (const float*)d_in[5];
    float* out = (float*)d_out;

    const int n = in_sizes[0] / XW;          // number of patients
    const int grid = (n + BLOCK - 1) / BLOCK;
    t1d_kernel<<<grid, BLOCK, 0, stream>>>(x, params, ai, cho, lq, lf, out, n);
}